// Round 4
// baseline (139.513 us; speedup 1.0000x reference)
//
#include <hip/hip_runtime.h>
#include <hip/hip_bf16.h>
#include <math.h>

#define N_ 8192
#define A_ 512
#define D_ 512
#define NN_ 3

// ---------------------------------------------------------------------------
// Kernel 0: sq[i] = ||a_i||^2. One wave per anchor.
// ---------------------------------------------------------------------------
__global__ __launch_bounds__(64) void sq_kernel(
    const float* __restrict__ anchors, float* __restrict__ sq) {
  const int i = blockIdx.x;
  const int l = threadIdx.x;
  const float4* a = reinterpret_cast<const float4*>(anchors + (size_t)i * D_);
  float s = 0.f;
  for (int k = l; k < D_ / 4; k += 64) {
    float4 v = a[k];
    s += v.x * v.x + v.y * v.y + v.z * v.z + v.w * v.w;
  }
#pragma unroll
  for (int d = 32; d > 0; d >>= 1) s += __shfl_down(s, d);
  if (l == 0) sq[i] = s;
}

// ---------------------------------------------------------------------------
// Kernel 1: full gram G = anchors @ anchors^T. Thread-per-output, 16x16 tile
// per block, grid 32x32 = 1024 blocks (4/CU, 16 waves/CU for latency hiding).
// Lanes share i-rows (4 distinct) and j-rows (16 distinct) -> HW broadcast.
// ---------------------------------------------------------------------------
__global__ __launch_bounds__(256) void gram_kernel(
    const float* __restrict__ anchors, float* __restrict__ G) {
  const int i = blockIdx.y * 16 + threadIdx.y;
  const int j = blockIdx.x * 16 + threadIdx.x;
  const float4* ai = reinterpret_cast<const float4*>(anchors + (size_t)i * D_);
  const float4* aj = reinterpret_cast<const float4*>(anchors + (size_t)j * D_);
  float a0 = 0.f, a1 = 0.f, a2 = 0.f, a3 = 0.f;
#pragma unroll 8
  for (int k = 0; k < D_ / 4; ++k) {
    float4 x = ai[k];
    float4 y = aj[k];
    a0 += x.x * y.x; a1 += x.y * y.y; a2 += x.z * y.z; a3 += x.w * y.w;
  }
  G[(size_t)i * A_ + j] = (a0 + a1) + (a2 + a3);
}

// ---------------------------------------------------------------------------
// Kernel 2: per-anchor 3-NN (from G,sq) + Cayley-Menger det. Block per anchor.
// ---------------------------------------------------------------------------
__global__ __launch_bounds__(256) void nn_det_kernel(
    const float* __restrict__ G, const float* __restrict__ sq,
    float* __restrict__ quality) {
  __shared__ float dist[A_];
  __shared__ float red[256];
  __shared__ int   redi[256];

  const int i = blockIdx.x;
  const int t = threadIdx.x;
  const float sqi = sq[i];
  const float* Grow = G + (size_t)i * A_;

  // dist exactly as reference: sqrt(max(sqi+sqj-2*dot,0)) + eye*1e12
  for (int j = t; j < A_; j += 256) {
    float d2 = fmaxf(sqi + sq[j] - 2.f * Grow[j], 0.f);
    float dd = sqrtf(d2);
    if (j == i) dd += 1e12f;
    dist[j] = dd;
  }
  __syncthreads();

  // 3x argmin with (value, index) lexicographic tie-break (stable argsort)
  int nn[NN_];
  for (int r = 0; r < NN_; ++r) {
    float best = 1e30f;
    int bi = 0x7fffffff;
    for (int j = t; j < A_; j += 256) {
      float v = dist[j];
      if (v < best || (v == best && j < bi)) { best = v; bi = j; }
    }
    red[t] = best; redi[t] = bi;
    __syncthreads();
    for (int s = 128; s > 0; s >>= 1) {
      if (t < s) {
        float ov = red[t + s]; int oi = redi[t + s];
        if (ov < red[t] || (ov == red[t] && oi < redi[t])) { red[t] = ov; redi[t] = oi; }
      }
      __syncthreads();
    }
    int w = redi[0];
    nn[r] = w;
    __syncthreads();
    if (t == 0) dist[w] = 1e30f;
    __syncthreads();
  }

  if (t == 0) {
    int idx[4] = { i, nn[0], nn[1], nn[2] };
    // Cayley-Menger 5x5 in double; d2 entries from G/sq in f32 like reference.
    double M[5][5];
    M[0][0] = 0.0;
    for (int q = 1; q < 5; ++q) { M[0][q] = 1.0; M[q][0] = 1.0; }
    for (int p = 0; p < 4; ++p)
      for (int q = 0; q < 4; ++q) {
        float d2f;
        if (p == q) {
          d2f = 0.0f;  // reference: diag_p + diag_p - 2*g_pp == 0 exactly
        } else {
          float g = G[(size_t)idx[p] * A_ + idx[q]];
          d2f = sq[idx[p]] + sq[idx[q]] - 2.f * g;
        }
        M[p + 1][q + 1] = (double)d2f;
      }

    double det = 1.0;
    for (int c = 0; c < 5; ++c) {
      int piv = c;
      double mx = fabs(M[c][c]);
      for (int r2 = c + 1; r2 < 5; ++r2) {
        double v = fabs(M[r2][c]);
        if (v > mx) { mx = v; piv = r2; }
      }
      if (piv != c) {
        for (int c2 = 0; c2 < 5; ++c2) { double tmp = M[c][c2]; M[c][c2] = M[piv][c2]; M[piv][c2] = tmp; }
        det = -det;
      }
      double pv = M[c][c];
      det *= pv;
      if (pv == 0.0) break;
      for (int r2 = c + 1; r2 < 5; ++r2) {
        double f = M[r2][c] / pv;
        for (int c2 = c; c2 < 5; ++c2) M[r2][c2] -= f * M[c][c2];
      }
    }
    float raw = (float)det;
    float sg = (raw > 0.f) ? 1.f : ((raw < 0.f) ? -1.f : 0.f);
    quality[i] = sg * logf(fabsf(raw) + 1e-12f);
  }
}

// ---------------------------------------------------------------------------
// Kernel 3: normalize quality -> (q - mean) / max(std_ddof1, 1e-8). 1 block.
// ---------------------------------------------------------------------------
__global__ __launch_bounds__(A_) void norm_cm_kernel(
    const float* __restrict__ quality, float* __restrict__ cmn) {
  __shared__ float red[A_];
  const int t = threadIdx.x;
  float q = quality[t];
  red[t] = q;
  __syncthreads();
  for (int s = A_ / 2; s > 0; s >>= 1) {
    if (t < s) red[t] += red[t + s];
    __syncthreads();
  }
  float mean = red[0] * (1.0f / A_);
  __syncthreads();
  float dq = q - mean;
  red[t] = dq * dq;
  __syncthreads();
  for (int s = A_ / 2; s > 0; s >>= 1) {
    if (t < s) red[t] += red[t + s];
    __syncthreads();
  }
  float sd = sqrtf(red[0] * (1.0f / (A_ - 1)));
  sd = fmaxf(sd, 1e-8f);
  cmn[t] = dq / sd;
}

// ---------------------------------------------------------------------------
// Kernel 4: bucket-histogram stable rank + gate MLP + sigmoid. (unchanged)
// ---------------------------------------------------------------------------
__global__ __launch_bounds__(A_) void gate_kernel_bucket(
    const float* __restrict__ tri, const float* __restrict__ cmn,
    const float* __restrict__ W1, const float* __restrict__ b1,
    const float* __restrict__ W2, const float* __restrict__ b2,
    float* __restrict__ out) {
  __shared__ int hist[256];
  __shared__ int pref[256];
  __shared__ int cursor[256];
  __shared__ unsigned long long sorted[A_];

  const int n = blockIdx.x;
  const int t = threadIdx.x;

  const float ti = tri[(size_t)n * A_ + t];
  const unsigned long long key =
      ((unsigned long long)__float_as_uint(ti) << 9) | (unsigned)t;
  int b = (int)(ti * 128.0f);
  b = (b < 0) ? 0 : ((b > 255) ? 255 : b);

  if (t < 256) { hist[t] = 0; cursor[t] = 0; }
  __syncthreads();
  atomicAdd(&hist[b], 1);
  __syncthreads();

  if (t < 64) {
    const int b4 = t * 4;
    int h0 = hist[b4 + 0], h1 = hist[b4 + 1], h2 = hist[b4 + 2], h3 = hist[b4 + 3];
    int s = h0 + h1 + h2 + h3;
    int incl = s;
#pragma unroll
    for (int d = 1; d < 64; d <<= 1) {
      int u = __shfl_up(incl, d);
      if (t >= d) incl += u;
    }
    int ex = incl - s;
    pref[b4 + 0] = ex;
    pref[b4 + 1] = ex + h0;
    pref[b4 + 2] = ex + h0 + h1;
    pref[b4 + 3] = ex + h0 + h1 + h2;
  }
  __syncthreads();

  const int pos = pref[b] + atomicAdd(&cursor[b], 1);
  sorted[pos] = key;
  __syncthreads();

  const int start = pref[b];
  const int len = hist[b];
  int cnt = start;
  for (int m = 0; m < len; ++m) cnt += (sorted[start + m] < key);
  const float rank = (float)cnt * (1.0f / (A_ - 1));

  const float f0 = cmn[t];
  const float f1 = 1.0f - ti;

  float logit = b2[0];
#pragma unroll
  for (int k = 0; k < 16; ++k) {
    float x = W1[k * 3 + 0] * f0 + W1[k * 3 + 1] * f1 + W1[k * 3 + 2] * rank + b1[k];
    float g = 0.5f * x * (1.0f + erff(x * 0.70710678118654752440f));
    logit += W2[k] * g;
  }
  out[(size_t)n * A_ + t] = 1.0f / (1.0f + expf(-logit));
}

// ---------------------------------------------------------------------------
extern "C" void kernel_launch(void* const* d_in, const int* in_sizes, int n_in,
                              void* d_out, int out_size, void* d_ws, size_t ws_size,
                              hipStream_t stream) {
  // inputs: 0 embedding (unused), 1 anchors, 2 tri, 3 W1, 4 b1, 5 W2, 6 b2
  const float* anchors = (const float*)d_in[1];
  const float* tri     = (const float*)d_in[2];
  const float* W1      = (const float*)d_in[3];
  const float* b1      = (const float*)d_in[4];
  const float* W2      = (const float*)d_in[5];
  const float* b2      = (const float*)d_in[6];
  float* out = (float*)d_out;

  float* G       = (float*)d_ws;              // A_*A_ floats (1 MB)
  float* sq      = G + (size_t)A_ * A_;       // A_ floats
  float* quality = sq + A_;                   // A_ floats
  float* cmn     = quality + A_;              // A_ floats

  sq_kernel<<<A_, 64, 0, stream>>>(anchors, sq);
  gram_kernel<<<dim3(A_ / 16, A_ / 16), dim3(16, 16), 0, stream>>>(anchors, G);
  nn_det_kernel<<<A_, 256, 0, stream>>>(G, sq, quality);
  norm_cm_kernel<<<1, A_, 0, stream>>>(quality, cmn);
  gate_kernel_bucket<<<N_, A_, 0, stream>>>(tri, cmn, W1, b1, W2, b2, out);
}

// Round 5
// 90.435 us; speedup vs baseline: 1.5427x; 1.5427x over previous
//
#include <hip/hip_runtime.h>
#include <hip/hip_bf16.h>
#include <math.h>

#define N_ 8192
#define A_ 512
#define D_ 512
#define NN_ 3

// ---------------------------------------------------------------------------
// Kernel 0: sq[i] = ||a_i||^2. One wave per anchor.
// ---------------------------------------------------------------------------
__global__ __launch_bounds__(64) void sq_kernel(
    const float* __restrict__ anchors, float* __restrict__ sq) {
  const int i = blockIdx.x;
  const int l = threadIdx.x;
  const float4* a = reinterpret_cast<const float4*>(anchors + (size_t)i * D_);
  float s = 0.f;
  for (int k = l; k < D_ / 4; k += 64) {
    float4 v = a[k];
    s += v.x * v.x + v.y * v.y + v.z * v.z + v.w * v.w;
  }
#pragma unroll
  for (int d = 32; d > 0; d >>= 1) s += __shfl_down(s, d);
  if (l == 0) sq[i] = s;
}

// ---------------------------------------------------------------------------
// Kernel 1: G = anchors @ anchors^T via LDS-tiled GEMM.
// 64x64 tile per block (grid 8x8), BK=32, k-major LDS (At[kk][row]) with
// 68-float row pitch (272B, 16B-aligned) so fragment reads are ds_read_b128.
// Global staging is row-segment coalesced (8 lanes x 16B per row).
// ---------------------------------------------------------------------------
__global__ __launch_bounds__(256) void gram_tiled_kernel(
    const float* __restrict__ anchors, float* __restrict__ G) {
  __shared__ float At[32][68];
  __shared__ float Bt[32][68];

  const int tx = threadIdx.x;          // 0..15
  const int ty = threadIdx.y;          // 0..15
  const int tid = ty * 16 + tx;
  const int i0 = blockIdx.y * 64;
  const int j0 = blockIdx.x * 64;

  const int r0 = tid >> 3;             // 0..31
  const int c4 = tid & 7;              // 0..7 (which float4 of the 32-col tile)

  float acc[4][4];
#pragma unroll
  for (int m = 0; m < 4; ++m)
#pragma unroll
    for (int n = 0; n < 4; ++n) acc[m][n] = 0.f;

  for (int kt = 0; kt < 16; ++kt) {
    const int kb = kt * 32 + c4 * 4;
    // issue global loads before the barrier (prefetch over previous compute)
    float4 va = *reinterpret_cast<const float4*>(&anchors[(size_t)(i0 + r0) * D_ + kb]);
    float4 vb = *reinterpret_cast<const float4*>(&anchors[(size_t)(i0 + r0 + 32) * D_ + kb]);
    float4 wa = *reinterpret_cast<const float4*>(&anchors[(size_t)(j0 + r0) * D_ + kb]);
    float4 wb = *reinterpret_cast<const float4*>(&anchors[(size_t)(j0 + r0 + 32) * D_ + kb]);
    __syncthreads();   // previous iteration's LDS reads done
    const int kc = c4 * 4;
    At[kc + 0][r0] = va.x; At[kc + 1][r0] = va.y; At[kc + 2][r0] = va.z; At[kc + 3][r0] = va.w;
    At[kc + 0][r0 + 32] = vb.x; At[kc + 1][r0 + 32] = vb.y; At[kc + 2][r0 + 32] = vb.z; At[kc + 3][r0 + 32] = vb.w;
    Bt[kc + 0][r0] = wa.x; Bt[kc + 1][r0] = wa.y; Bt[kc + 2][r0] = wa.z; Bt[kc + 3][r0] = wa.w;
    Bt[kc + 0][r0 + 32] = wb.x; Bt[kc + 1][r0 + 32] = wb.y; Bt[kc + 2][r0 + 32] = wb.z; Bt[kc + 3][r0 + 32] = wb.w;
    __syncthreads();

#pragma unroll
    for (int kk = 0; kk < 32; ++kk) {
      float4 a = *reinterpret_cast<const float4*>(&At[kk][ty * 4]);
      float4 b = *reinterpret_cast<const float4*>(&Bt[kk][tx * 4]);
      acc[0][0] += a.x * b.x; acc[0][1] += a.x * b.y; acc[0][2] += a.x * b.z; acc[0][3] += a.x * b.w;
      acc[1][0] += a.y * b.x; acc[1][1] += a.y * b.y; acc[1][2] += a.y * b.z; acc[1][3] += a.y * b.w;
      acc[2][0] += a.z * b.x; acc[2][1] += a.z * b.y; acc[2][2] += a.z * b.z; acc[2][3] += a.z * b.w;
      acc[3][0] += a.w * b.x; acc[3][1] += a.w * b.y; acc[3][2] += a.w * b.z; acc[3][3] += a.w * b.w;
    }
  }

#pragma unroll
  for (int m = 0; m < 4; ++m) {
    float4 st;
    st.x = acc[m][0]; st.y = acc[m][1]; st.z = acc[m][2]; st.w = acc[m][3];
    *reinterpret_cast<float4*>(&G[(size_t)(i0 + ty * 4 + m) * A_ + j0 + tx * 4]) = st;
  }
}

// ---------------------------------------------------------------------------
// Kernel 2: per-anchor 3-NN (from G,sq) + Cayley-Menger det. One WAVE per
// anchor: dist in 8 regs/lane, shfl_xor butterfly lex-argmin, no barriers.
// ---------------------------------------------------------------------------
__device__ __forceinline__ void lexmin(float& v, int& j, float ov, int oj) {
  if (ov < v || (ov == v && oj < j)) { v = ov; j = oj; }
}

__global__ __launch_bounds__(64) void nn_det_kernel(
    const float* __restrict__ G, const float* __restrict__ sq,
    float* __restrict__ quality) {
  __shared__ float d2s[16];
  const int i = blockIdx.x;
  const int l = threadIdx.x;
  const float sqi = sq[i];
  const float* Grow = G + (size_t)i * A_;
  const int jb = l * 8;

  float4 g0 = *reinterpret_cast<const float4*>(&Grow[jb]);
  float4 g1 = *reinterpret_cast<const float4*>(&Grow[jb + 4]);
  float4 s0 = *reinterpret_cast<const float4*>(&sq[jb]);
  float4 s1 = *reinterpret_cast<const float4*>(&sq[jb + 4]);

  float dist[8];
  {
    float gg[8] = { g0.x, g0.y, g0.z, g0.w, g1.x, g1.y, g1.z, g1.w };
    float ss[8] = { s0.x, s0.y, s0.z, s0.w, s1.x, s1.y, s1.z, s1.w };
#pragma unroll
    for (int q = 0; q < 8; ++q) {
      float d2 = fmaxf(sqi + ss[q] - 2.f * gg[q], 0.f);
      float dd = sqrtf(d2);
      if (jb + q == i) dd += 1e12f;
      dist[q] = dd;
    }
  }

  int nn[NN_];
#pragma unroll
  for (int r = 0; r < NN_; ++r) {
    float bv = 1e30f;
    int bi = 0x7fffffff;
#pragma unroll
    for (int q = 0; q < 8; ++q) lexmin(bv, bi, dist[q], jb + q);
#pragma unroll
    for (int d = 1; d < 64; d <<= 1) {
      float ov = __shfl_xor(bv, d);
      int oi = __shfl_xor(bi, d);
      lexmin(bv, bi, ov, oi);
    }
    nn[r] = bi;  // identical on all lanes
#pragma unroll
    for (int q = 0; q < 8; ++q)
      if (jb + q == bi) dist[q] = 1e30f;
  }

  // d2 entries: 16 lanes fetch in parallel (one L2 latency instead of 16)
  if (l < 16) {
    const int p = l >> 2, q = l & 3;
    const int pi = (p == 0) ? i : ((p == 1) ? nn[0] : ((p == 2) ? nn[1] : nn[2]));
    const int qi = (q == 0) ? i : ((q == 1) ? nn[0] : ((q == 2) ? nn[1] : nn[2]));
    float d2f;
    if (p == q) {
      d2f = 0.f;  // reference: diag_p + diag_p - 2*g_pp == 0 exactly
    } else {
      float g = G[(size_t)pi * A_ + qi];
      d2f = sq[pi] + sq[qi] - 2.f * g;
    }
    d2s[l] = d2f;
  }
  __syncthreads();

  if (l == 0) {
    double M[5][5];
    M[0][0] = 0.0;
    for (int q = 1; q < 5; ++q) { M[0][q] = 1.0; M[q][0] = 1.0; }
    for (int p = 0; p < 4; ++p)
      for (int q = 0; q < 4; ++q)
        M[p + 1][q + 1] = (double)d2s[p * 4 + q];

    double det = 1.0;
    for (int c = 0; c < 5; ++c) {
      int piv = c;
      double mx = fabs(M[c][c]);
      for (int r2 = c + 1; r2 < 5; ++r2) {
        double v = fabs(M[r2][c]);
        if (v > mx) { mx = v; piv = r2; }
      }
      if (piv != c) {
        for (int c2 = 0; c2 < 5; ++c2) { double tmp = M[c][c2]; M[c][c2] = M[piv][c2]; M[piv][c2] = tmp; }
        det = -det;
      }
      double pv = M[c][c];
      det *= pv;
      if (pv == 0.0) break;
      for (int r2 = c + 1; r2 < 5; ++r2) {
        double f = M[r2][c] / pv;
        for (int c2 = c; c2 < 5; ++c2) M[r2][c2] -= f * M[c][c2];
      }
    }
    float raw = (float)det;
    float sg = (raw > 0.f) ? 1.f : ((raw < 0.f) ? -1.f : 0.f);
    quality[i] = sg * logf(fabsf(raw) + 1e-12f);
  }
}

// ---------------------------------------------------------------------------
// Kernel 3: normalize quality -> (q - mean) / max(std_ddof1, 1e-8). 1 block.
// ---------------------------------------------------------------------------
__global__ __launch_bounds__(A_) void norm_cm_kernel(
    const float* __restrict__ quality, float* __restrict__ cmn) {
  __shared__ float red[A_];
  const int t = threadIdx.x;
  float q = quality[t];
  red[t] = q;
  __syncthreads();
  for (int s = A_ / 2; s > 0; s >>= 1) {
    if (t < s) red[t] += red[t + s];
    __syncthreads();
  }
  float mean = red[0] * (1.0f / A_);
  __syncthreads();
  float dq = q - mean;
  red[t] = dq * dq;
  __syncthreads();
  for (int s = A_ / 2; s > 0; s >>= 1) {
    if (t < s) red[t] += red[t + s];
    __syncthreads();
  }
  float sd = sqrtf(red[0] * (1.0f / (A_ - 1)));
  sd = fmaxf(sd, 1e-8f);
  cmn[t] = dq / sd;
}

// ---------------------------------------------------------------------------
// Kernel 4: bucket-histogram stable rank + gate MLP + sigmoid. (unchanged)
// ---------------------------------------------------------------------------
__global__ __launch_bounds__(A_) void gate_kernel_bucket(
    const float* __restrict__ tri, const float* __restrict__ cmn,
    const float* __restrict__ W1, const float* __restrict__ b1,
    const float* __restrict__ W2, const float* __restrict__ b2,
    float* __restrict__ out) {
  __shared__ int hist[256];
  __shared__ int pref[256];
  __shared__ int cursor[256];
  __shared__ unsigned long long sorted[A_];

  const int n = blockIdx.x;
  const int t = threadIdx.x;

  const float ti = tri[(size_t)n * A_ + t];
  const unsigned long long key =
      ((unsigned long long)__float_as_uint(ti) << 9) | (unsigned)t;
  int b = (int)(ti * 128.0f);
  b = (b < 0) ? 0 : ((b > 255) ? 255 : b);

  if (t < 256) { hist[t] = 0; cursor[t] = 0; }
  __syncthreads();
  atomicAdd(&hist[b], 1);
  __syncthreads();

  if (t < 64) {
    const int b4 = t * 4;
    int h0 = hist[b4 + 0], h1 = hist[b4 + 1], h2 = hist[b4 + 2], h3 = hist[b4 + 3];
    int s = h0 + h1 + h2 + h3;
    int incl = s;
#pragma unroll
    for (int d = 1; d < 64; d <<= 1) {
      int u = __shfl_up(incl, d);
      if (t >= d) incl += u;
    }
    int ex = incl - s;
    pref[b4 + 0] = ex;
    pref[b4 + 1] = ex + h0;
    pref[b4 + 2] = ex + h0 + h1;
    pref[b4 + 3] = ex + h0 + h1 + h2;
  }
  __syncthreads();

  const int pos = pref[b] + atomicAdd(&cursor[b], 1);
  sorted[pos] = key;
  __syncthreads();

  const int start = pref[b];
  const int len = hist[b];
  int cnt = start;
  for (int m = 0; m < len; ++m) cnt += (sorted[start + m] < key);
  const float rank = (float)cnt * (1.0f / (A_ - 1));

  const float f0 = cmn[t];
  const float f1 = 1.0f - ti;

  float logit = b2[0];
#pragma unroll
  for (int k = 0; k < 16; ++k) {
    float x = W1[k * 3 + 0] * f0 + W1[k * 3 + 1] * f1 + W1[k * 3 + 2] * rank + b1[k];
    float g = 0.5f * x * (1.0f + erff(x * 0.70710678118654752440f));
    logit += W2[k] * g;
  }
  out[(size_t)n * A_ + t] = 1.0f / (1.0f + expf(-logit));
}

// ---------------------------------------------------------------------------
extern "C" void kernel_launch(void* const* d_in, const int* in_sizes, int n_in,
                              void* d_out, int out_size, void* d_ws, size_t ws_size,
                              hipStream_t stream) {
  // inputs: 0 embedding (unused), 1 anchors, 2 tri, 3 W1, 4 b1, 5 W2, 6 b2
  const float* anchors = (const float*)d_in[1];
  const float* tri     = (const float*)d_in[2];
  const float* W1      = (const float*)d_in[3];
  const float* b1      = (const float*)d_in[4];
  const float* W2      = (const float*)d_in[5];
  const float* b2      = (const float*)d_in[6];
  float* out = (float*)d_out;

  float* G       = (float*)d_ws;              // A_*A_ floats (1 MB)
  float* sq      = G + (size_t)A_ * A_;       // A_ floats
  float* quality = sq + A_;                   // A_ floats
  float* cmn     = quality + A_;              // A_ floats

  sq_kernel<<<A_, 64, 0, stream>>>(anchors, sq);
  gram_tiled_kernel<<<dim3(8, 8), dim3(16, 16), 0, stream>>>(anchors, G);
  nn_det_kernel<<<A_, 64, 0, stream>>>(G, sq, quality);
  norm_cm_kernel<<<1, A_, 0, stream>>>(quality, cmn);
  gate_kernel_bucket<<<N_, A_, 0, stream>>>(tri, cmn, W1, b1, W2, b2, out);
}